// Round 14
// baseline (513.429 us; speedup 1.0000x reference)
//
#include <hip/hip_runtime.h>
#include <hip/hip_fp16.h>

#define N_NODES 50000
#define N_EDGES 1600000
#define H 64
#define IN_CH 7
#define EDIM 4
#define G_GRAPHS 256
#define FC 128
#define NC 2
#define SLOPE 0.2f
#define SCAN_BLOCKS ((N_NODES + 255) / 256)   // 196
#define NPRIV 32

typedef _Float16 h2v __attribute__((ext_vector_type(2)));
typedef int i4v __attribute__((ext_vector_type(4)));

__device__ __forceinline__ float fdot2f(h2v a, h2v b, float c) {
#if defined(__has_builtin) && __has_builtin(__builtin_amdgcn_fdot2)
    return __builtin_amdgcn_fdot2(a, b, c, false);
#else
    return c + (float)a[0] * (float)b[0] + (float)a[1] * (float)b[1];
#endif
}

// ---------------- DPP wave-64 reductions ----------------
__device__ __forceinline__ float wave_sum_to63(float x) {
    x += __int_as_float(__builtin_amdgcn_update_dpp(0, __float_as_int(x), 0x111, 0xf, 0xf, true)); // row_shr:1
    x += __int_as_float(__builtin_amdgcn_update_dpp(0, __float_as_int(x), 0x112, 0xf, 0xf, true)); // row_shr:2
    x += __int_as_float(__builtin_amdgcn_update_dpp(0, __float_as_int(x), 0x114, 0xf, 0xf, true)); // row_shr:4
    x += __int_as_float(__builtin_amdgcn_update_dpp(0, __float_as_int(x), 0x118, 0xf, 0xf, true)); // row_shr:8
    x += __int_as_float(__builtin_amdgcn_update_dpp(0, __float_as_int(x), 0x142, 0xf, 0xf, true)); // row_bcast:15
    x += __int_as_float(__builtin_amdgcn_update_dpp(0, __float_as_int(x), 0x143, 0xf, 0xf, true)); // row_bcast:31
    return x;
}
__device__ __forceinline__ float wave_max_to63(float x) {
    int xi = __float_as_int(x);
    x = fmaxf(x, __int_as_float(__builtin_amdgcn_update_dpp(xi, xi, 0x111, 0xf, 0xf, false))); xi = __float_as_int(x);
    x = fmaxf(x, __int_as_float(__builtin_amdgcn_update_dpp(xi, xi, 0x112, 0xf, 0xf, false))); xi = __float_as_int(x);
    x = fmaxf(x, __int_as_float(__builtin_amdgcn_update_dpp(xi, xi, 0x114, 0xf, 0xf, false))); xi = __float_as_int(x);
    x = fmaxf(x, __int_as_float(__builtin_amdgcn_update_dpp(xi, xi, 0x118, 0xf, 0xf, false))); xi = __float_as_int(x);
    x = fmaxf(x, __int_as_float(__builtin_amdgcn_update_dpp(xi, xi, 0x142, 0xf, 0xf, false))); xi = __float_as_int(x);
    x = fmaxf(x, __int_as_float(__builtin_amdgcn_update_dpp(xi, xi, 0x143, 0xf, 0xf, false)));
    return x;
}
__device__ __forceinline__ float lane63_bcast(float x) {
    return __int_as_float(__builtin_amdgcn_readlane(__float_as_int(x), 63));
}
__device__ __forceinline__ float readlane_f(float x, int i) {
    return __int_as_float(__builtin_amdgcn_readlane(__float_as_int(x), i));
}

// ---------------- CSR build ----------------
// pass 1: privatized histogram (32 copies; block b -> copy b&31) + rank-in-copy.
// Rank order within a dst row is free (softmax/sum are permutation-invariant).
__global__ void rank_kernel(const int* __restrict__ dst, int* __restrict__ deg_priv,
                            int* __restrict__ rank) {
    int e = blockIdx.x * blockDim.x + threadIdx.x;
    if (e >= N_EDGES) return;
    int k = blockIdx.x & (NPRIV - 1);
    int r = atomicAdd(&deg_priv[k * N_NODES + dst[e]], 1);
    __builtin_nontemporal_store(r, &rank[e]);
}

// fused: per-node exclusive prefix across 32 copies (in place) + total degree + block sums
__global__ void scan_combine_kernel(int* __restrict__ deg_priv, int* __restrict__ deg,
                                    int* __restrict__ bsum) {
    __shared__ int lds[256];
    int b = blockIdx.x, t = threadIdx.x;
    int idx = b * 256 + t;
    int tot = 0;
    if (idx < N_NODES) {
        int c[NPRIV];
#pragma unroll
        for (int k = 0; k < NPRIV; ++k) c[k] = deg_priv[k * N_NODES + idx];
#pragma unroll
        for (int k = 0; k < NPRIV; ++k) { int v = c[k]; deg_priv[k * N_NODES + idx] = tot; tot += v; }
        deg[idx] = tot;
    }
    lds[t] = tot;
    __syncthreads();
    for (int off = 128; off >= 1; off >>= 1) {
        if (t < off) lds[t] += lds[t + off];
        __syncthreads();
    }
    if (t == 0) bsum[b] = lds[0];
}

__global__ void scan_top_kernel(const int* __restrict__ bsum, int* __restrict__ boff) {
    __shared__ int lds[256];
    int t = threadIdx.x;
    int v = (t < SCAN_BLOCKS) ? bsum[t] : 0;
    lds[t] = v;
    __syncthreads();
    for (int off = 1; off < 256; off <<= 1) {
        int x = (t >= off) ? lds[t - off] : 0;
        __syncthreads();
        lds[t] += x;
        __syncthreads();
    }
    boff[t] = lds[t] - v;   // exclusive
}

__global__ void scan_final_kernel(const int* __restrict__ deg, const int* __restrict__ boff,
                                  int* __restrict__ row_start) {
    __shared__ int lds[256];
    int b = blockIdx.x, t = threadIdx.x;
    int idx = b * 256 + t;
    int v = (idx < N_NODES) ? deg[idx] : 0;
    lds[t] = v;
    __syncthreads();
    for (int off = 1; off < 256; off <<= 1) {
        int x = (t >= off) ? lds[t - off] : 0;
        __syncthreads();
        lds[t] += x;
        __syncthreads();
    }
    int excl = boff[b] + lds[t] - v;
    if (idx < N_NODES) {
        row_start[idx] = excl;
        if (idx == N_NODES - 1) row_start[N_NODES] = excl + v;
    }
}

// pass 2: non-atomic scatter of packed 16B entries {src, fp16x2(ea01), fp16x2(ea23), dst}
__global__ void scatter_kernel(const int* __restrict__ src, const int* __restrict__ dst,
                               const int* __restrict__ rank, const int* __restrict__ row_start,
                               const int* __restrict__ deg_priv,
                               const float* __restrict__ edge_attr,
                               i4v* __restrict__ csr) {
    int e = blockIdx.x * blockDim.x + threadIdx.x;
    if (e >= N_EDGES) return;
    int d = dst[e];
    int k = (e >> 8) & (NPRIV - 1);
    int slot = row_start[d] + deg_priv[k * N_NODES + d] + rank[e];
    float4 ea = ((const float4*)edge_attr)[e];
    __half2 h01 = __floats2half2_rn(ea.x, ea.y);
    __half2 h23 = __floats2half2_rn(ea.z, ea.w);
    i4v ent;
    ent.x = src[e];
    ent.y = *reinterpret_cast<int*>(&h01);
    ent.z = *reinterpret_cast<int*>(&h23);
    ent.w = d;
    __builtin_nontemporal_store(ent, &csr[slot]);
}

// fused prep: weh0/weh1 packing + transposed layer-1 proj weights wt/bb
__global__ void prep_kernel(const float* __restrict__ We0, const float* __restrict__ We1,
                            const float* __restrict__ Wl1, const float* __restrict__ bl1,
                            const float* __restrict__ Wr1, const float* __restrict__ br1,
                            __half2* __restrict__ weh0, __half2* __restrict__ weh1,
                            __half2* __restrict__ wt, float* __restrict__ bb) {
    int t = threadIdx.x;
    if (t < 32) {
        for (int k = 0; k < 4; ++k)
            weh0[t * 4 + k] = __floats2half2_rn(We0[k * H + 2 * t], We0[k * H + 2 * t + 1]);
    } else if (t < 64) {
        int c = t - 32;
        for (int k = 0; k < 4; ++k)
            weh1[c * 4 + k] = __floats2half2_rn(We1[k * H + 2 * c], We1[k * H + 2 * c + 1]);
    }
    if (t < 128) {
        const float* W = (t < 64) ? Wl1 : Wr1;
        int c = t & 63;
        for (int kk = 0; kk < 32; ++kk)
            wt[t * 32 + kk] = __floats2half2_rn(W[(2 * kk) * H + c], W[(2 * kk + 1) * H + c]);
        bb[t] = (t < 64) ? bl1[c] : br1[c];
    }
}

// ---------------- layer-0 projection (K=7) -> packed fp16 channel pairs ----------------
__global__ void proj0_kernel(const float* __restrict__ xin,
                             const float* __restrict__ Wl, const float* __restrict__ bl,
                             const float* __restrict__ Wr, const float* __restrict__ br,
                             __half2* __restrict__ xlh, __half2* __restrict__ xrh) {
    int idx = blockIdx.x * blockDim.x + threadIdx.x;
    if (idx >= N_NODES * 32) return;
    int n = idx >> 5;
    int c = idx & 31;
    const float* xi = xin + n * IN_CH;
    float2 bl2 = ((const float2*)bl)[c];
    float2 br2 = ((const float2*)br)[c];
    float al0 = bl2.x, al1 = bl2.y, ar0 = br2.x, ar1 = br2.y;
#pragma unroll
    for (int k = 0; k < IN_CH; ++k) {
        float xv = xi[k];
        float2 wl2 = ((const float2*)(Wl + k * H))[c];
        float2 wr2 = ((const float2*)(Wr + k * H))[c];
        al0 += xv * wl2.x; al1 += xv * wl2.y;
        ar0 += xv * wr2.x; ar1 += xv * wr2.y;
    }
    xlh[idx] = __floats2half2_rn(al0, al1);
    xrh[idx] = __floats2half2_rn(ar0, ar1);
}

// ---------------- layer-1 projection: lane = node, scalar weights ----------------
__global__ __launch_bounds__(256) void proj1_kernel(
        const float* __restrict__ xin,        // C fp32 [N,64]
        const __half2* __restrict__ wt,       // [128][32] half2
        const float* __restrict__ bb,         // [128]
        __half2* __restrict__ xlh, __half2* __restrict__ xrh) {
    int g = __builtin_amdgcn_readfirstlane((int)(threadIdx.x >> 6));  // chan group 0..3
    int lane = threadIdx.x & 63;
    int node = blockIdx.x * 64 + lane;
    if (node >= N_NODES) return;

    h2v xrow[32];
    const float4* xp = (const float4*)(xin + node * 64);
#pragma unroll
    for (int q = 0; q < 16; ++q) {
        float4 v = xp[q];
        __half2 a = __floats2half2_rn(v.x, v.y);
        __half2 b = __floats2half2_rn(v.z, v.w);
        xrow[2 * q]     = *reinterpret_cast<h2v*>(&a);
        xrow[2 * q + 1] = *reinterpret_cast<h2v*>(&b);
    }

    __half2* outp = (g < 2) ? xlh : xrh;
    int chbase = g * 32;
    int localbase = (g & 1) * 16;

#pragma unroll
    for (int cp = 0; cp < 16; ++cp) {
        int ch0 = chbase + 2 * cp;
        const h2v* w0 = (const h2v*)(wt + ch0 * 32);
        const h2v* w1 = (const h2v*)(wt + (ch0 + 1) * 32);
        float a0 = bb[ch0], a1 = bb[ch0 + 1];
#pragma unroll
        for (int kk = 0; kk < 32; ++kk) {
            a0 = fdot2f(xrow[kk], w0[kk], a0);
            a1 = fdot2f(xrow[kk], w1[kk], a1);
        }
        outp[node * 32 + localbase + cp] = __floats2half2_rn(a0, a1);
    }
}

// ---------------- pass A: per-edge score, lane = edge ----------------
__global__ __launch_bounds__(256) void score_kernel(
        const int4* __restrict__ csr,
        const __half2* __restrict__ xlh, const __half2* __restrict__ xrh,
        const __half2* __restrict__ weh, const float* __restrict__ att,
        float* __restrict__ score) {
    int e = blockIdx.x * blockDim.x + threadIdx.x;
    if (e >= N_EDGES) return;
    int4 ent = csr[e];
    __half2 ea01 = *reinterpret_cast<__half2*>(&ent.y);
    __half2 ea23 = *reinterpret_cast<__half2*>(&ent.z);
    __half2 e0 = __half2half2(__low2half(ea01));
    __half2 e1 = __half2half2(__high2half(ea01));
    __half2 e2 = __half2half2(__low2half(ea23));
    __half2 e3 = __half2half2(__high2half(ea23));
    const int4* xa = (const int4*)(xlh + ent.x * 32);
    const int4* xb = (const int4*)(xrh + ent.w * 32);
    float acc0 = 0.f, acc1 = 0.f;
#pragma unroll
    for (int k = 0; k < 8; ++k) {
        int4 va = xa[k];
        int4 vb = xb[k];
        const __half2* ha = reinterpret_cast<const __half2*>(&va);
        const __half2* hc = reinterpret_cast<const __half2*>(&vb);
#pragma unroll
        for (int j = 0; j < 4; ++j) {
            int c = k * 4 + j;                     // uniform -> scalar loads
            __half2 v2 = __hadd2(ha[j], hc[j]);
            v2 = __hfma2(e0, weh[c * 4 + 0], v2);
            v2 = __hfma2(e1, weh[c * 4 + 1], v2);
            v2 = __hfma2(e2, weh[c * 4 + 2], v2);
            v2 = __hfma2(e3, weh[c * 4 + 3], v2);
            float2 vf = __half22float2(v2);
            float L0 = fmaxf(vf.x, SLOPE * vf.x);  // leaky_relu (slope<1)
            float L1 = fmaxf(vf.y, SLOPE * vf.y);
            float2 a2 = ((const float2*)att)[c];
            acc0 += L0 * a2.x;
            acc1 += L1 * a2.y;
        }
    }
    score[e] = acc0 + acc1;
}

// ---------------- pass B: aggregation, one wave per node ----------------
__global__ __launch_bounds__(256) void agg_kernel(
        const int* __restrict__ row_start,
        const int4* __restrict__ csr,
        const float* __restrict__ score,
        const __half2* __restrict__ xlh,
        const float* __restrict__ bias,
        float* __restrict__ out) {
    int wave = (blockIdx.x * blockDim.x + threadIdx.x) >> 6;
    if (wave >= N_NODES) return;
    int lane = threadIdx.x & 63;
    int c = lane & 31;
    int hb = lane >> 5;
    int d = wave;
    int beg = __builtin_amdgcn_readfirstlane(row_start[d]);
    int end = __builtin_amdgcn_readfirstlane(row_start[d + 1]);

    float m = -INFINITY;
    for (int j = beg + lane; j < end; j += 64) m = fmaxf(m, score[j]);
    m = lane63_bcast(wave_max_to63(m));

    float l_lane = 0.f;
    float ax0 = 0.f, ay0 = 0.f, ax1 = 0.f, ay1 = 0.f;

    for (int cbeg = beg; cbeg < end; cbeg += 64) {
        int n = end - cbeg;
        int idx = cbeg + lane;
        float sc = score[min(idx, end - 1)];
        float p = __expf(sc - m);
        p = (lane < n) ? p : 0.f;
        l_lane += p;

        int nn = min(n, 64);
        int j = 0;
        for (; j + 4 <= nn; j += 4) {
            int sA0 = __builtin_amdgcn_readfirstlane(csr[cbeg + j + 0].x);
            int sB0 = __builtin_amdgcn_readfirstlane(csr[cbeg + j + 1].x);
            int sA1 = __builtin_amdgcn_readfirstlane(csr[cbeg + j + 2].x);
            int sB1 = __builtin_amdgcn_readfirstlane(csr[cbeg + j + 3].x);
            float pA0 = readlane_f(p, j + 0), pB0 = readlane_f(p, j + 1);
            float pA1 = readlane_f(p, j + 2), pB1 = readlane_f(p, j + 3);
            int s0 = hb ? sB0 : sA0;
            int s1 = hb ? sB1 : sA1;
            float pv0 = hb ? pB0 : pA0;
            float pv1 = hb ? pB1 : pA1;
            float2 x0 = __half22float2(xlh[s0 * 32 + c]);
            float2 x1 = __half22float2(xlh[s1 * 32 + c]);
            ax0 += pv0 * x0.x; ay0 += pv0 * x0.y;
            ax1 += pv1 * x1.x; ay1 += pv1 * x1.y;
        }
        for (; j + 2 <= nn; j += 2) {
            int sA = __builtin_amdgcn_readfirstlane(csr[cbeg + j + 0].x);
            int sB = __builtin_amdgcn_readfirstlane(csr[cbeg + j + 1].x);
            float pA = readlane_f(p, j + 0), pB = readlane_f(p, j + 1);
            int s = hb ? sB : sA;
            float pv = hb ? pB : pA;
            float2 xf = __half22float2(xlh[s * 32 + c]);
            ax0 += pv * xf.x; ay0 += pv * xf.y;
        }
        if (j < nn) {
            int sA = __builtin_amdgcn_readfirstlane(csr[cbeg + j].x);
            float pA = readlane_f(p, j);
            float pv = hb ? 0.f : pA;
            float2 xf = __half22float2(xlh[sA * 32 + c]);
            ax0 += pv * xf.x; ay0 += pv * xf.y;
        }
    }

    float l = lane63_bcast(wave_sum_to63(l_lane));
    float accx = ax0 + ax1, accy = ay0 + ay1;
    accx += __shfl_xor(accx, 32, 64);
    accy += __shfl_xor(accy, 32, 64);
    if (hb == 0) {
        float inv = 1.f / (l + 1e-16f);
        float2 b2 = ((const float2*)bias)[c];
        float o0 = accx * inv + b2.x;
        float o1 = accy * inv + b2.y;
        o0 = o0 > 0.f ? o0 : expm1f(o0);
        o1 = o1 > 0.f ? o1 : expm1f(o1);
        ((float2*)out)[d * 32 + c] = float2{o0, o1};
    }
}

// ---------------- fused pool + head: one block per graph ----------------
__global__ __launch_bounds__(256) void pool_head_kernel(
        const float* __restrict__ h, const int* __restrict__ batch,
        const float* __restrict__ fc1w, const float* __restrict__ fc1b,
        const float* __restrict__ fc2w, const float* __restrict__ fc2b,
        float* __restrict__ out) {
    int g = blockIdx.x;
    int lo = 0, hi = N_NODES;
    while (lo < hi) { int mid = (lo + hi) >> 1; if (batch[mid] < g) lo = mid + 1; else hi = mid; }
    int start = lo;
    hi = N_NODES;
    while (lo < hi) { int mid = (lo + hi) >> 1; if (batch[mid] < g + 1) lo = mid + 1; else hi = mid; }
    int end = lo;

    int lane = threadIdx.x & 63;
    int w = threadIdx.x >> 6;
    float s = 0.f;
    for (int n = start + w; n < end; n += 4) s += h[n * H + lane];
    __shared__ float red[4][H];
    __shared__ float gv[H];
    __shared__ float f[FC];
    __shared__ float lg[NC];
    red[w][lane] = s;
    __syncthreads();
    if (w == 0) {
        float tot = red[0][lane] + red[1][lane] + red[2][lane] + red[3][lane];
        gv[lane] = tot / fmaxf((float)(end - start), 1.f);
    }
    __syncthreads();
    int t = threadIdx.x;
    if (t < FC) {
        float acc = fc1b[t];
#pragma unroll 16
        for (int k = 0; k < H; ++k) acc += gv[k] * fc1w[k * FC + t];
        f[t] = fmaxf(acc, 0.f);
    }
    __syncthreads();
    if (t < NC) {
        float a = fc2b[t];
        for (int k = 0; k < FC; ++k) a += f[k] * fc2w[k * NC + t];
        lg[t] = a;
    }
    __syncthreads();
    if (t < NC) {
        float mx = fmaxf(lg[0], lg[1]);
        float lse = mx + logf(expf(lg[0] - mx) + expf(lg[1] - mx));
        out[g * NC + t] = lg[t] - lse;
    }
}

extern "C" void kernel_launch(void* const* d_in, const int* in_sizes, int n_in,
                              void* d_out, int out_size, void* d_ws, size_t ws_size,
                              hipStream_t stream) {
    const float* x         = (const float*)d_in[0];
    const int*   edge_idx  = (const int*)d_in[1];
    const float* edge_attr = (const float*)d_in[2];
    const int*   batch     = (const int*)d_in[3];
    const float* Wl0  = (const float*)d_in[4];
    const float* bl0  = (const float*)d_in[5];
    const float* Wr0  = (const float*)d_in[6];
    const float* br0  = (const float*)d_in[7];
    const float* We0  = (const float*)d_in[8];
    const float* att0 = (const float*)d_in[9];
    const float* bias0= (const float*)d_in[10];
    const float* Wl1  = (const float*)d_in[11];
    const float* bl1  = (const float*)d_in[12];
    const float* Wr1  = (const float*)d_in[13];
    const float* br1  = (const float*)d_in[14];
    const float* We1  = (const float*)d_in[15];
    const float* att1 = (const float*)d_in[16];
    const float* bias1= (const float*)d_in[17];
    const float* fc1w = (const float*)d_in[18];
    const float* fc1b = (const float*)d_in[19];
    const float* fc2w = (const float*)d_in[20];
    const float* fc2b = (const float*)d_in[21];

    const int NH = N_NODES * H;
    __half2* xlh    = (__half2*)d_ws;                 // [N*32]
    __half2* xrh    = xlh + N_NODES * 32;             // [N*32]
    float* C        = (float*)(xrh + N_NODES * 32);   // layer output [N,H] fp32
    int*   deg      = (int*)(C + NH);                 // [N]
    int*   row_start= deg + N_NODES;                  // [N+1]
    int*   bsum     = row_start + N_NODES + 1;        // [256]
    int*   boff     = bsum + 256;                     // [256]
    __half2* weh0   = (__half2*)(boff + 256);         // [128]
    __half2* weh1   = weh0 + 128;                     // [128]
    __half2* wt1    = weh1 + 128;                     // [128*32]
    float* bb1      = (float*)(wt1 + 128 * 32);       // [128]
    int*   deg_priv = (int*)(bb1 + 128);              // [32*N]
    char*  after    = (char*)(deg_priv + NPRIV * N_NODES);
    size_t csr_off  = (((size_t)(after - (char*)d_ws)) + 15) & ~(size_t)15;
    i4v*   csr      = (i4v*)((char*)d_ws + csr_off);  // [E] packed 16B
    float* escore   = (float*)((char*)csr + (size_t)N_EDGES * sizeof(i4v)); // [E]
    float* gmean    = escore + N_EDGES;               // [G,H] (pad)
    int*   rank     = (int*)(gmean + G_GRAPHS * H);   // [E]

    const int* src = edge_idx;
    const int* dst = edge_idx + N_EDGES;

    const int pairBlocks = (N_NODES * 32 + 255) / 256;
    const int edgeBlocks = (N_EDGES + 255) / 256;
    const int waveBlocks = (N_NODES * 64 + 255) / 256;
    const int p1Blocks   = (N_NODES + 63) / 64;

    // ---- CSR build ----
    (void)hipMemsetAsync(deg_priv, 0, (size_t)NPRIV * N_NODES * sizeof(int), stream);
    rank_kernel<<<edgeBlocks, 256, 0, stream>>>(dst, deg_priv, rank);
    scan_combine_kernel<<<SCAN_BLOCKS, 256, 0, stream>>>(deg_priv, deg, bsum);
    scan_top_kernel<<<1, 256, 0, stream>>>(bsum, boff);
    scan_final_kernel<<<SCAN_BLOCKS, 256, 0, stream>>>(deg, boff, row_start);
    scatter_kernel<<<edgeBlocks, 256, 0, stream>>>(src, dst, rank, row_start, deg_priv, edge_attr, csr);
    prep_kernel<<<1, 128, 0, stream>>>(We0, We1, Wl1, bl1, Wr1, br1, weh0, weh1, wt1, bb1);

    // ---- layer 0 ----
    proj0_kernel<<<pairBlocks, 256, 0, stream>>>(x, Wl0, bl0, Wr0, br0, xlh, xrh);
    score_kernel<<<edgeBlocks, 256, 0, stream>>>((const int4*)csr, xlh, xrh, weh0, att0, escore);
    agg_kernel<<<waveBlocks, 256, 0, stream>>>(row_start, (const int4*)csr, escore, xlh, bias0, C);

    // ---- layer 1 ----
    proj1_kernel<<<p1Blocks, 256, 0, stream>>>(C, wt1, bb1, xlh, xrh);
    score_kernel<<<edgeBlocks, 256, 0, stream>>>((const int4*)csr, xlh, xrh, weh1, att1, escore);
    agg_kernel<<<waveBlocks, 256, 0, stream>>>(row_start, (const int4*)csr, escore, xlh, bias1, C);

    // ---- pool + head (fused) ----
    pool_head_kernel<<<G_GRAPHS, 256, 0, stream>>>(C, batch, fc1w, fc1b, fc2w, fc2b, (float*)d_out);
}

// Round 15
// 480.166 us; speedup vs baseline: 1.0693x; 1.0693x over previous
//
#include <hip/hip_runtime.h>
#include <hip/hip_fp16.h>

#define N_NODES 50000
#define N_EDGES 1600000
#define H 64
#define IN_CH 7
#define EDIM 4
#define G_GRAPHS 256
#define FC 128
#define NC 2
#define SLOPE 0.2f
#define SCAN_BLOCKS ((N_NODES + 255) / 256)   // 196
#define NPRIV 8
#define RANK_BLOCKS ((N_EDGES + 255) / 256)        // 6250
#define PAIR_BLOCKS ((N_NODES * 32 + 255) / 256)   // 6250

typedef _Float16 h2v __attribute__((ext_vector_type(2)));

__device__ __forceinline__ float fdot2f(h2v a, h2v b, float c) {
#if defined(__has_builtin) && __has_builtin(__builtin_amdgcn_fdot2)
    return __builtin_amdgcn_fdot2(a, b, c, false);
#else
    return c + (float)a[0] * (float)b[0] + (float)a[1] * (float)b[1];
#endif
}

// ---------------- DPP wave-64 reductions ----------------
__device__ __forceinline__ float wave_sum_to63(float x) {
    x += __int_as_float(__builtin_amdgcn_update_dpp(0, __float_as_int(x), 0x111, 0xf, 0xf, true)); // row_shr:1
    x += __int_as_float(__builtin_amdgcn_update_dpp(0, __float_as_int(x), 0x112, 0xf, 0xf, true)); // row_shr:2
    x += __int_as_float(__builtin_amdgcn_update_dpp(0, __float_as_int(x), 0x114, 0xf, 0xf, true)); // row_shr:4
    x += __int_as_float(__builtin_amdgcn_update_dpp(0, __float_as_int(x), 0x118, 0xf, 0xf, true)); // row_shr:8
    x += __int_as_float(__builtin_amdgcn_update_dpp(0, __float_as_int(x), 0x142, 0xf, 0xf, true)); // row_bcast:15
    x += __int_as_float(__builtin_amdgcn_update_dpp(0, __float_as_int(x), 0x143, 0xf, 0xf, true)); // row_bcast:31
    return x;
}
__device__ __forceinline__ float wave_max_to63(float x) {
    int xi = __float_as_int(x);
    x = fmaxf(x, __int_as_float(__builtin_amdgcn_update_dpp(xi, xi, 0x111, 0xf, 0xf, false))); xi = __float_as_int(x);
    x = fmaxf(x, __int_as_float(__builtin_amdgcn_update_dpp(xi, xi, 0x112, 0xf, 0xf, false))); xi = __float_as_int(x);
    x = fmaxf(x, __int_as_float(__builtin_amdgcn_update_dpp(xi, xi, 0x114, 0xf, 0xf, false))); xi = __float_as_int(x);
    x = fmaxf(x, __int_as_float(__builtin_amdgcn_update_dpp(xi, xi, 0x118, 0xf, 0xf, false))); xi = __float_as_int(x);
    x = fmaxf(x, __int_as_float(__builtin_amdgcn_update_dpp(xi, xi, 0x142, 0xf, 0xf, false))); xi = __float_as_int(x);
    x = fmaxf(x, __int_as_float(__builtin_amdgcn_update_dpp(xi, xi, 0x143, 0xf, 0xf, false)));
    return x;
}
__device__ __forceinline__ float lane63_bcast(float x) {
    return __int_as_float(__builtin_amdgcn_readlane(__float_as_int(x), 63));
}
__device__ __forceinline__ float readlane_f(float x, int i) {
    return __int_as_float(__builtin_amdgcn_readlane(__float_as_int(x), i));
}

// ---------------- fused front-end: rank (atomic histogram) + proj0 + prep ----------------
// rank is latency-bound (VALU 0.5%, HBM 11%); proj0/prep ride in its shadow.
__global__ __launch_bounds__(256) void front_kernel(
        const int* __restrict__ dst, int* __restrict__ deg_priv, int* __restrict__ rank,
        const float* __restrict__ xin,
        const float* __restrict__ Wl0, const float* __restrict__ bl0,
        const float* __restrict__ Wr0, const float* __restrict__ br0,
        __half2* __restrict__ xlh, __half2* __restrict__ xrh,
        const float* __restrict__ We0, const float* __restrict__ We1,
        const float* __restrict__ Wl1, const float* __restrict__ bl1,
        const float* __restrict__ Wr1, const float* __restrict__ br1,
        __half2* __restrict__ weh0, __half2* __restrict__ weh1,
        __half2* __restrict__ wt, float* __restrict__ bb) {
    int b = blockIdx.x;
    int t = threadIdx.x;
    if (b < RANK_BLOCKS) {
        // ---- rank: privatized histogram (8 copies; block -> copy b&7) ----
        int e = b * 256 + t;
        if (e < N_EDGES) {
            int k = b & (NPRIV - 1);
            rank[e] = atomicAdd(&deg_priv[k * N_NODES + dst[e]], 1);
        }
    } else if (b < RANK_BLOCKS + PAIR_BLOCKS) {
        // ---- proj0: (node, channel-pair) ----
        int idx = (b - RANK_BLOCKS) * 256 + t;
        if (idx < N_NODES * 32) {
            int n = idx >> 5;
            int c = idx & 31;
            const float* xi = xin + n * IN_CH;
            float2 bl2 = ((const float2*)bl0)[c];
            float2 br2 = ((const float2*)br0)[c];
            float al0 = bl2.x, al1 = bl2.y, ar0 = br2.x, ar1 = br2.y;
#pragma unroll
            for (int k = 0; k < IN_CH; ++k) {
                float xv = xi[k];
                float2 wl2 = ((const float2*)(Wl0 + k * H))[c];
                float2 wr2 = ((const float2*)(Wr0 + k * H))[c];
                al0 += xv * wl2.x; al1 += xv * wl2.y;
                ar0 += xv * wr2.x; ar1 += xv * wr2.y;
            }
            xlh[idx] = __floats2half2_rn(al0, al1);
            xrh[idx] = __floats2half2_rn(ar0, ar1);
        }
    } else {
        // ---- prep: weh0/weh1 + transposed layer-1 weights ----
        if (t < 32) {
            for (int k = 0; k < 4; ++k)
                weh0[t * 4 + k] = __floats2half2_rn(We0[k * H + 2 * t], We0[k * H + 2 * t + 1]);
        } else if (t < 64) {
            int c = t - 32;
            for (int k = 0; k < 4; ++k)
                weh1[c * 4 + k] = __floats2half2_rn(We1[k * H + 2 * c], We1[k * H + 2 * c + 1]);
        }
        if (t < 128) {
            const float* W = (t < 64) ? Wl1 : Wr1;
            int c = t & 63;
            for (int kk = 0; kk < 32; ++kk)
                wt[t * 32 + kk] = __floats2half2_rn(W[(2 * kk) * H + c], W[(2 * kk + 1) * H + c]);
            bb[t] = (t < 64) ? bl1[c] : br1[c];
        }
    }
}

// fused: per-node exclusive prefix across 8 copies (in place) + total degree + block sums
__global__ void scan_combine_kernel(int* __restrict__ deg_priv, int* __restrict__ deg,
                                    int* __restrict__ bsum) {
    __shared__ int lds[256];
    int b = blockIdx.x, t = threadIdx.x;
    int idx = b * 256 + t;
    int tot = 0;
    if (idx < N_NODES) {
        int c[NPRIV];
#pragma unroll
        for (int k = 0; k < NPRIV; ++k) c[k] = deg_priv[k * N_NODES + idx];
#pragma unroll
        for (int k = 0; k < NPRIV; ++k) { int v = c[k]; deg_priv[k * N_NODES + idx] = tot; tot += v; }
        deg[idx] = tot;
    }
    lds[t] = tot;
    __syncthreads();
    for (int off = 128; off >= 1; off >>= 1) {
        if (t < off) lds[t] += lds[t + off];
        __syncthreads();
    }
    if (t == 0) bsum[b] = lds[0];
}

__global__ void scan_top_kernel(const int* __restrict__ bsum, int* __restrict__ boff) {
    __shared__ int lds[256];
    int t = threadIdx.x;
    int v = (t < SCAN_BLOCKS) ? bsum[t] : 0;
    lds[t] = v;
    __syncthreads();
    for (int off = 1; off < 256; off <<= 1) {
        int x = (t >= off) ? lds[t - off] : 0;
        __syncthreads();
        lds[t] += x;
        __syncthreads();
    }
    boff[t] = lds[t] - v;   // exclusive
}

__global__ void scan_final_kernel(const int* __restrict__ deg, const int* __restrict__ boff,
                                  int* __restrict__ row_start) {
    __shared__ int lds[256];
    int b = blockIdx.x, t = threadIdx.x;
    int idx = b * 256 + t;
    int v = (idx < N_NODES) ? deg[idx] : 0;
    lds[t] = v;
    __syncthreads();
    for (int off = 1; off < 256; off <<= 1) {
        int x = (t >= off) ? lds[t - off] : 0;
        __syncthreads();
        lds[t] += x;
        __syncthreads();
    }
    int excl = boff[b] + lds[t] - v;
    if (idx < N_NODES) {
        row_start[idx] = excl;
        if (idx == N_NODES - 1) row_start[N_NODES] = excl + v;
    }
}

// pass 2: non-atomic scatter of packed 16B entries {src, fp16x2(ea01), fp16x2(ea23), dst}
__global__ void scatter_kernel(const int* __restrict__ src, const int* __restrict__ dst,
                               const int* __restrict__ rank, const int* __restrict__ row_start,
                               const int* __restrict__ deg_priv,
                               const float* __restrict__ edge_attr,
                               int4* __restrict__ csr) {
    int e = blockIdx.x * blockDim.x + threadIdx.x;
    if (e >= N_EDGES) return;
    int d = dst[e];
    int k = (e >> 8) & (NPRIV - 1);
    int slot = row_start[d] + deg_priv[k * N_NODES + d] + rank[e];
    float4 ea = ((const float4*)edge_attr)[e];
    __half2 h01 = __floats2half2_rn(ea.x, ea.y);
    __half2 h23 = __floats2half2_rn(ea.z, ea.w);
    int4 ent;
    ent.x = src[e];
    ent.y = *reinterpret_cast<int*>(&h01);
    ent.z = *reinterpret_cast<int*>(&h23);
    ent.w = d;
    csr[slot] = ent;
}

// ---------------- layer-1 projection: lane = node, scalar weights ----------------
__global__ __launch_bounds__(256) void proj1_kernel(
        const float* __restrict__ xin,        // C fp32 [N,64]
        const __half2* __restrict__ wt,       // [128][32] half2
        const float* __restrict__ bb,         // [128]
        __half2* __restrict__ xlh, __half2* __restrict__ xrh) {
    int g = __builtin_amdgcn_readfirstlane((int)(threadIdx.x >> 6));  // chan group 0..3
    int lane = threadIdx.x & 63;
    int node = blockIdx.x * 64 + lane;
    if (node >= N_NODES) return;

    h2v xrow[32];
    const float4* xp = (const float4*)(xin + node * 64);
#pragma unroll
    for (int q = 0; q < 16; ++q) {
        float4 v = xp[q];
        __half2 a = __floats2half2_rn(v.x, v.y);
        __half2 b = __floats2half2_rn(v.z, v.w);
        xrow[2 * q]     = *reinterpret_cast<h2v*>(&a);
        xrow[2 * q + 1] = *reinterpret_cast<h2v*>(&b);
    }

    __half2* outp = (g < 2) ? xlh : xrh;
    int chbase = g * 32;
    int localbase = (g & 1) * 16;

#pragma unroll
    for (int cp = 0; cp < 16; ++cp) {
        int ch0 = chbase + 2 * cp;
        const h2v* w0 = (const h2v*)(wt + ch0 * 32);
        const h2v* w1 = (const h2v*)(wt + (ch0 + 1) * 32);
        float a0 = bb[ch0], a1 = bb[ch0 + 1];
#pragma unroll
        for (int kk = 0; kk < 32; ++kk) {
            a0 = fdot2f(xrow[kk], w0[kk], a0);
            a1 = fdot2f(xrow[kk], w1[kk], a1);
        }
        outp[node * 32 + localbase + cp] = __floats2half2_rn(a0, a1);
    }
}

// ---------------- pass A: per-edge score, lane = edge ----------------
__global__ __launch_bounds__(256) void score_kernel(
        const int4* __restrict__ csr,
        const __half2* __restrict__ xlh, const __half2* __restrict__ xrh,
        const __half2* __restrict__ weh, const float* __restrict__ att,
        float* __restrict__ score) {
    int e = blockIdx.x * blockDim.x + threadIdx.x;
    if (e >= N_EDGES) return;
    int4 ent = csr[e];
    __half2 ea01 = *reinterpret_cast<__half2*>(&ent.y);
    __half2 ea23 = *reinterpret_cast<__half2*>(&ent.z);
    __half2 e0 = __half2half2(__low2half(ea01));
    __half2 e1 = __half2half2(__high2half(ea01));
    __half2 e2 = __half2half2(__low2half(ea23));
    __half2 e3 = __half2half2(__high2half(ea23));
    const int4* xa = (const int4*)(xlh + ent.x * 32);
    const int4* xb = (const int4*)(xrh + ent.w * 32);
    float acc0 = 0.f, acc1 = 0.f;
#pragma unroll
    for (int k = 0; k < 8; ++k) {
        int4 va = xa[k];
        int4 vb = xb[k];
        const __half2* ha = reinterpret_cast<const __half2*>(&va);
        const __half2* hc = reinterpret_cast<const __half2*>(&vb);
#pragma unroll
        for (int j = 0; j < 4; ++j) {
            int c = k * 4 + j;                     // uniform -> scalar loads
            __half2 v2 = __hadd2(ha[j], hc[j]);
            v2 = __hfma2(e0, weh[c * 4 + 0], v2);
            v2 = __hfma2(e1, weh[c * 4 + 1], v2);
            v2 = __hfma2(e2, weh[c * 4 + 2], v2);
            v2 = __hfma2(e3, weh[c * 4 + 3], v2);
            float2 vf = __half22float2(v2);
            float L0 = fmaxf(vf.x, SLOPE * vf.x);  // leaky_relu (slope<1)
            float L1 = fmaxf(vf.y, SLOPE * vf.y);
            float2 a2 = ((const float2*)att)[c];
            acc0 += L0 * a2.x;
            acc1 += L1 * a2.y;
        }
    }
    score[e] = acc0 + acc1;
}

// ---------------- pass B: aggregation, one wave per node ----------------
__global__ __launch_bounds__(256) void agg_kernel(
        const int* __restrict__ row_start,
        const int4* __restrict__ csr,
        const float* __restrict__ score,
        const __half2* __restrict__ xlh,
        const float* __restrict__ bias,
        float* __restrict__ out) {
    int wave = (blockIdx.x * blockDim.x + threadIdx.x) >> 6;
    if (wave >= N_NODES) return;
    int lane = threadIdx.x & 63;
    int c = lane & 31;
    int hb = lane >> 5;
    int d = wave;
    int beg = __builtin_amdgcn_readfirstlane(row_start[d]);
    int end = __builtin_amdgcn_readfirstlane(row_start[d + 1]);

    float m = -INFINITY;
    for (int j = beg + lane; j < end; j += 64) m = fmaxf(m, score[j]);
    m = lane63_bcast(wave_max_to63(m));

    float l_lane = 0.f;
    float ax0 = 0.f, ay0 = 0.f, ax1 = 0.f, ay1 = 0.f;

    for (int cbeg = beg; cbeg < end; cbeg += 64) {
        int n = end - cbeg;
        int idx = cbeg + lane;
        float sc = score[min(idx, end - 1)];
        float p = __expf(sc - m);
        p = (lane < n) ? p : 0.f;
        l_lane += p;

        int nn = min(n, 64);
        int j = 0;
        for (; j + 4 <= nn; j += 4) {
            int sA0 = __builtin_amdgcn_readfirstlane(csr[cbeg + j + 0].x);
            int sB0 = __builtin_amdgcn_readfirstlane(csr[cbeg + j + 1].x);
            int sA1 = __builtin_amdgcn_readfirstlane(csr[cbeg + j + 2].x);
            int sB1 = __builtin_amdgcn_readfirstlane(csr[cbeg + j + 3].x);
            float pA0 = readlane_f(p, j + 0), pB0 = readlane_f(p, j + 1);
            float pA1 = readlane_f(p, j + 2), pB1 = readlane_f(p, j + 3);
            int s0 = hb ? sB0 : sA0;
            int s1 = hb ? sB1 : sA1;
            float pv0 = hb ? pB0 : pA0;
            float pv1 = hb ? pB1 : pA1;
            float2 x0 = __half22float2(xlh[s0 * 32 + c]);
            float2 x1 = __half22float2(xlh[s1 * 32 + c]);
            ax0 += pv0 * x0.x; ay0 += pv0 * x0.y;
            ax1 += pv1 * x1.x; ay1 += pv1 * x1.y;
        }
        for (; j + 2 <= nn; j += 2) {
            int sA = __builtin_amdgcn_readfirstlane(csr[cbeg + j + 0].x);
            int sB = __builtin_amdgcn_readfirstlane(csr[cbeg + j + 1].x);
            float pA = readlane_f(p, j + 0), pB = readlane_f(p, j + 1);
            int s = hb ? sB : sA;
            float pv = hb ? pB : pA;
            float2 xf = __half22float2(xlh[s * 32 + c]);
            ax0 += pv * xf.x; ay0 += pv * xf.y;
        }
        if (j < nn) {
            int sA = __builtin_amdgcn_readfirstlane(csr[cbeg + j].x);
            float pA = readlane_f(p, j);
            float pv = hb ? 0.f : pA;
            float2 xf = __half22float2(xlh[sA * 32 + c]);
            ax0 += pv * xf.x; ay0 += pv * xf.y;
        }
    }

    float l = lane63_bcast(wave_sum_to63(l_lane));
    float accx = ax0 + ax1, accy = ay0 + ay1;
    accx += __shfl_xor(accx, 32, 64);
    accy += __shfl_xor(accy, 32, 64);
    if (hb == 0) {
        float inv = 1.f / (l + 1e-16f);
        float2 b2 = ((const float2*)bias)[c];
        float o0 = accx * inv + b2.x;
        float o1 = accy * inv + b2.y;
        o0 = o0 > 0.f ? o0 : expm1f(o0);
        o1 = o1 > 0.f ? o1 : expm1f(o1);
        ((float2*)out)[d * 32 + c] = float2{o0, o1};
    }
}

// ---------------- fused pool + head: one block per graph ----------------
__global__ __launch_bounds__(256) void pool_head_kernel(
        const float* __restrict__ h, const int* __restrict__ batch,
        const float* __restrict__ fc1w, const float* __restrict__ fc1b,
        const float* __restrict__ fc2w, const float* __restrict__ fc2b,
        float* __restrict__ out) {
    int g = blockIdx.x;
    int lo = 0, hi = N_NODES;
    while (lo < hi) { int mid = (lo + hi) >> 1; if (batch[mid] < g) lo = mid + 1; else hi = mid; }
    int start = lo;
    hi = N_NODES;
    while (lo < hi) { int mid = (lo + hi) >> 1; if (batch[mid] < g + 1) lo = mid + 1; else hi = mid; }
    int end = lo;

    int lane = threadIdx.x & 63;
    int w = threadIdx.x >> 6;
    float s = 0.f;
    for (int n = start + w; n < end; n += 4) s += h[n * H + lane];
    __shared__ float red[4][H];
    __shared__ float gv[H];
    __shared__ float f[FC];
    __shared__ float lg[NC];
    red[w][lane] = s;
    __syncthreads();
    if (w == 0) {
        float tot = red[0][lane] + red[1][lane] + red[2][lane] + red[3][lane];
        gv[lane] = tot / fmaxf((float)(end - start), 1.f);
    }
    __syncthreads();
    int t = threadIdx.x;
    if (t < FC) {
        float acc = fc1b[t];
#pragma unroll 16
        for (int k = 0; k < H; ++k) acc += gv[k] * fc1w[k * FC + t];
        f[t] = fmaxf(acc, 0.f);
    }
    __syncthreads();
    if (t < NC) {
        float a = fc2b[t];
        for (int k = 0; k < FC; ++k) a += f[k] * fc2w[k * NC + t];
        lg[t] = a;
    }
    __syncthreads();
    if (t < NC) {
        float mx = fmaxf(lg[0], lg[1]);
        float lse = mx + logf(expf(lg[0] - mx) + expf(lg[1] - mx));
        out[g * NC + t] = lg[t] - lse;
    }
}

extern "C" void kernel_launch(void* const* d_in, const int* in_sizes, int n_in,
                              void* d_out, int out_size, void* d_ws, size_t ws_size,
                              hipStream_t stream) {
    const float* x         = (const float*)d_in[0];
    const int*   edge_idx  = (const int*)d_in[1];
    const float* edge_attr = (const float*)d_in[2];
    const int*   batch     = (const int*)d_in[3];
    const float* Wl0  = (const float*)d_in[4];
    const float* bl0  = (const float*)d_in[5];
    const float* Wr0  = (const float*)d_in[6];
    const float* br0  = (const float*)d_in[7];
    const float* We0  = (const float*)d_in[8];
    const float* att0 = (const float*)d_in[9];
    const float* bias0= (const float*)d_in[10];
    const float* Wl1  = (const float*)d_in[11];
    const float* bl1  = (const float*)d_in[12];
    const float* Wr1  = (const float*)d_in[13];
    const float* br1  = (const float*)d_in[14];
    const float* We1  = (const float*)d_in[15];
    const float* att1 = (const float*)d_in[16];
    const float* bias1= (const float*)d_in[17];
    const float* fc1w = (const float*)d_in[18];
    const float* fc1b = (const float*)d_in[19];
    const float* fc2w = (const float*)d_in[20];
    const float* fc2b = (const float*)d_in[21];

    const int NH = N_NODES * H;
    __half2* xlh    = (__half2*)d_ws;                 // [N*32]
    __half2* xrh    = xlh + N_NODES * 32;             // [N*32]
    float* C        = (float*)(xrh + N_NODES * 32);   // layer output [N,H] fp32
    int*   deg      = (int*)(C + NH);                 // [N]
    int*   row_start= deg + N_NODES;                  // [N+1]
    int*   bsum     = row_start + N_NODES + 1;        // [256]
    int*   boff     = bsum + 256;                     // [256]
    __half2* weh0   = (__half2*)(boff + 256);         // [128]
    __half2* weh1   = weh0 + 128;                     // [128]
    __half2* wt1    = weh1 + 128;                     // [128*32]
    float* bb1      = (float*)(wt1 + 128 * 32);       // [128]
    int*   deg_priv = (int*)(bb1 + 128);              // [8*N]
    char*  after    = (char*)(deg_priv + NPRIV * N_NODES);
    size_t csr_off  = (((size_t)(after - (char*)d_ws)) + 15) & ~(size_t)15;
    int4*  csr      = (int4*)((char*)d_ws + csr_off); // [E] packed 16B
    float* escore   = (float*)((char*)csr + (size_t)N_EDGES * sizeof(int4)); // [E]
    float* gmean    = escore + N_EDGES;               // pad
    int*   rank     = (int*)(gmean + G_GRAPHS * H);   // [E]

    const int* src = edge_idx;
    const int* dst = edge_idx + N_EDGES;

    const int edgeBlocks = (N_EDGES + 255) / 256;
    const int waveBlocks = (N_NODES * 64 + 255) / 256;
    const int p1Blocks   = (N_NODES + 63) / 64;
    const int frontBlocks = RANK_BLOCKS + PAIR_BLOCKS + 1;

    // ---- fused front-end: rank + proj0 + prep (independent; overlap) ----
    (void)hipMemsetAsync(deg_priv, 0, (size_t)NPRIV * N_NODES * sizeof(int), stream);
    front_kernel<<<frontBlocks, 256, 0, stream>>>(dst, deg_priv, rank,
                                                  x, Wl0, bl0, Wr0, br0, xlh, xrh,
                                                  We0, We1, Wl1, bl1, Wr1, br1,
                                                  weh0, weh1, wt1, bb1);
    scan_combine_kernel<<<SCAN_BLOCKS, 256, 0, stream>>>(deg_priv, deg, bsum);
    scan_top_kernel<<<1, 256, 0, stream>>>(bsum, boff);
    scan_final_kernel<<<SCAN_BLOCKS, 256, 0, stream>>>(deg, boff, row_start);
    scatter_kernel<<<edgeBlocks, 256, 0, stream>>>(src, dst, rank, row_start, deg_priv, edge_attr, csr);

    // ---- layer 0 ----
    score_kernel<<<edgeBlocks, 256, 0, stream>>>(csr, xlh, xrh, weh0, att0, escore);
    agg_kernel<<<waveBlocks, 256, 0, stream>>>(row_start, csr, escore, xlh, bias0, C);

    // ---- layer 1 ----
    proj1_kernel<<<p1Blocks, 256, 0, stream>>>(C, wt1, bb1, xlh, xrh);
    score_kernel<<<edgeBlocks, 256, 0, stream>>>(csr, xlh, xrh, weh1, att1, escore);
    agg_kernel<<<waveBlocks, 256, 0, stream>>>(row_start, csr, escore, xlh, bias1, C);

    // ---- pool + head (fused) ----
    pool_head_kernel<<<G_GRAPHS, 256, 0, stream>>>(C, batch, fc1w, fc1b, fc2w, fc2b, (float*)d_out);
}

// Round 16
// 444.817 us; speedup vs baseline: 1.1542x; 1.0795x over previous
//
#include <hip/hip_runtime.h>
#include <hip/hip_fp16.h>

#define N_NODES 50000
#define N_EDGES 1600000
#define H 64
#define IN_CH 7
#define EDIM 4
#define G_GRAPHS 256
#define FC 128
#define NC 2
#define SLOPE 0.2f
#define NBUCK 196                      // coarse buckets: dst>>8, 50000>>8 = 195
#define EPB1 8192                      // edges per pass-1a block
#define NB1 ((N_EDGES + EPB1 - 1) / EPB1)          // 196
#define PAIR_BLOCKS ((N_NODES * 32 + 255) / 256)   // 6250

typedef _Float16 h2v __attribute__((ext_vector_type(2)));

__device__ __forceinline__ float fdot2f(h2v a, h2v b, float c) {
#if defined(__has_builtin) && __has_builtin(__builtin_amdgcn_fdot2)
    return __builtin_amdgcn_fdot2(a, b, c, false);
#else
    return c + (float)a[0] * (float)b[0] + (float)a[1] * (float)b[1];
#endif
}

// ---------------- DPP wave-64 reductions ----------------
__device__ __forceinline__ float wave_sum_to63(float x) {
    x += __int_as_float(__builtin_amdgcn_update_dpp(0, __float_as_int(x), 0x111, 0xf, 0xf, true)); // row_shr:1
    x += __int_as_float(__builtin_amdgcn_update_dpp(0, __float_as_int(x), 0x112, 0xf, 0xf, true)); // row_shr:2
    x += __int_as_float(__builtin_amdgcn_update_dpp(0, __float_as_int(x), 0x114, 0xf, 0xf, true)); // row_shr:4
    x += __int_as_float(__builtin_amdgcn_update_dpp(0, __float_as_int(x), 0x118, 0xf, 0xf, true)); // row_shr:8
    x += __int_as_float(__builtin_amdgcn_update_dpp(0, __float_as_int(x), 0x142, 0xf, 0xf, true)); // row_bcast:15
    x += __int_as_float(__builtin_amdgcn_update_dpp(0, __float_as_int(x), 0x143, 0xf, 0xf, true)); // row_bcast:31
    return x;
}
__device__ __forceinline__ float wave_max_to63(float x) {
    int xi = __float_as_int(x);
    x = fmaxf(x, __int_as_float(__builtin_amdgcn_update_dpp(xi, xi, 0x111, 0xf, 0xf, false))); xi = __float_as_int(x);
    x = fmaxf(x, __int_as_float(__builtin_amdgcn_update_dpp(xi, xi, 0x112, 0xf, 0xf, false))); xi = __float_as_int(x);
    x = fmaxf(x, __int_as_float(__builtin_amdgcn_update_dpp(xi, xi, 0x114, 0xf, 0xf, false))); xi = __float_as_int(x);
    x = fmaxf(x, __int_as_float(__builtin_amdgcn_update_dpp(xi, xi, 0x118, 0xf, 0xf, false))); xi = __float_as_int(x);
    x = fmaxf(x, __int_as_float(__builtin_amdgcn_update_dpp(xi, xi, 0x142, 0xf, 0xf, false))); xi = __float_as_int(x);
    x = fmaxf(x, __int_as_float(__builtin_amdgcn_update_dpp(xi, xi, 0x143, 0xf, 0xf, false)));
    return x;
}
__device__ __forceinline__ float lane63_bcast(float x) {
    return __int_as_float(__builtin_amdgcn_readlane(__float_as_int(x), 63));
}
__device__ __forceinline__ float readlane_f(float x, int i) {
    return __int_as_float(__builtin_amdgcn_readlane(__float_as_int(x), i));
}

// ---------------- fused front-end: coarse histogram+rank (LDS atomics) + proj0 + prep ----------------
__global__ __launch_bounds__(256) void front_kernel(
        const int* __restrict__ dst, int* __restrict__ rank1, int* __restrict__ bhist,
        const float* __restrict__ xin,
        const float* __restrict__ Wl0, const float* __restrict__ bl0,
        const float* __restrict__ Wr0, const float* __restrict__ br0,
        __half2* __restrict__ xlh, __half2* __restrict__ xrh,
        const float* __restrict__ We0, const float* __restrict__ We1,
        const float* __restrict__ Wl1, const float* __restrict__ bl1,
        const float* __restrict__ Wr1, const float* __restrict__ br1,
        __half2* __restrict__ weh0, __half2* __restrict__ weh1,
        __half2* __restrict__ wt, float* __restrict__ bb) {
    __shared__ int hist[NBUCK];
    int b = blockIdx.x;
    int t = threadIdx.x;
    if (b < NB1) {
        // ---- pass 1a: coarse bucket histogram + within-(block,bucket) rank ----
        if (t < NBUCK) hist[t] = 0;
        __syncthreads();
#pragma unroll
        for (int i = 0; i < EPB1 / 256; ++i) {
            int e = b * EPB1 + i * 256 + t;
            if (e < N_EDGES) {
                int k = dst[e] >> 8;
                rank1[e] = atomicAdd(&hist[k], 1);
            }
        }
        __syncthreads();
        if (t < NBUCK) bhist[b * NBUCK + t] = hist[t];
    } else if (b < NB1 + PAIR_BLOCKS) {
        // ---- proj0: (node, channel-pair) ----
        int idx = (b - NB1) * 256 + t;
        if (idx < N_NODES * 32) {
            int n = idx >> 5;
            int c = idx & 31;
            const float* xi = xin + n * IN_CH;
            float2 bl2 = ((const float2*)bl0)[c];
            float2 br2 = ((const float2*)br0)[c];
            float al0 = bl2.x, al1 = bl2.y, ar0 = br2.x, ar1 = br2.y;
#pragma unroll
            for (int k = 0; k < IN_CH; ++k) {
                float xv = xi[k];
                float2 wl2 = ((const float2*)(Wl0 + k * H))[c];
                float2 wr2 = ((const float2*)(Wr0 + k * H))[c];
                al0 += xv * wl2.x; al1 += xv * wl2.y;
                ar0 += xv * wr2.x; ar1 += xv * wr2.y;
            }
            xlh[idx] = __floats2half2_rn(al0, al1);
            xrh[idx] = __floats2half2_rn(ar0, ar1);
        }
    } else {
        // ---- prep: weh0/weh1 + transposed layer-1 weights ----
        if (t < 32) {
            for (int k = 0; k < 4; ++k)
                weh0[t * 4 + k] = __floats2half2_rn(We0[k * H + 2 * t], We0[k * H + 2 * t + 1]);
        } else if (t < 64) {
            int c = t - 32;
            for (int k = 0; k < 4; ++k)
                weh1[c * 4 + k] = __floats2half2_rn(We1[k * H + 2 * c], We1[k * H + 2 * c + 1]);
        }
        if (t < 128) {
            const float* W = (t < 64) ? Wl1 : Wr1;
            int c = t & 63;
            for (int kk = 0; kk < 32; ++kk)
                wt[t * 32 + kk] = __floats2half2_rn(W[(2 * kk) * H + c], W[(2 * kk + 1) * H + c]);
            bb[t] = (t < 64) ? bl1[c] : br1[c];
        }
    }
}

// single block: per-(block,bucket) bases + bucket starts
__global__ __launch_bounds__(256) void bucket_scan_kernel(
        const int* __restrict__ bhist, int* __restrict__ bases, int* __restrict__ cb_start) {
    __shared__ int lds[256];
    int t = threadIdx.x;
    int run = 0;
    if (t < NBUCK) {
        for (int b = 0; b < NB1; ++b) {
            bases[b * NBUCK + t] = run;     // block-relative offset within bucket t
            run += bhist[b * NBUCK + t];
        }
    }
    lds[t] = (t < NBUCK) ? run : 0;
    __syncthreads();
    for (int off = 1; off < 256; off <<= 1) {
        int x = (t >= off) ? lds[t - off] : 0;
        __syncthreads();
        lds[t] += x;
        __syncthreads();
    }
    if (t < NBUCK) cb_start[t] = lds[t] - run;   // exclusive
    if (t == NBUCK - 1) cb_start[NBUCK] = lds[t];
}

// coarse scatter: edge -> bucket-sorted tmp (writes land in short contiguous runs)
__global__ void coarse_scatter_kernel(const int* __restrict__ src, const int* __restrict__ dst,
                                      const int* __restrict__ rank1, const int* __restrict__ bases,
                                      const int* __restrict__ cb_start,
                                      const float* __restrict__ edge_attr,
                                      int4* __restrict__ tmp) {
    int e = blockIdx.x * blockDim.x + threadIdx.x;
    if (e >= N_EDGES) return;
    int d = dst[e];
    int k = d >> 8;
    int b = e / EPB1;
    int slot = cb_start[k] + bases[b * NBUCK + k] + rank1[e];
    float4 ea = ((const float4*)edge_attr)[e];
    __half2 h01 = __floats2half2_rn(ea.x, ea.y);
    __half2 h23 = __floats2half2_rn(ea.z, ea.w);
    int4 ent;
    ent.x = src[e];
    ent.y = *reinterpret_cast<int*>(&h01);
    ent.z = *reinterpret_cast<int*>(&h23);
    ent.w = d;
    tmp[slot] = ent;
}

// fine sort: one block per coarse bucket (256 dst nodes); emits csr + row_start.
__global__ __launch_bounds__(256) void fine_sort_kernel(
        const int* __restrict__ cb_start, const int4* __restrict__ tmp,
        int4* __restrict__ csr, int* __restrict__ row_start) {
    __shared__ int hist2[256];
    __shared__ int cursor[256];
    __shared__ int lds[256];
    int k = blockIdx.x;
    int t = threadIdx.x;
    int beg = cb_start[k], end = cb_start[k + 1];
    hist2[t] = 0;
    __syncthreads();
    for (int i = beg + t; i < end; i += 256)
        atomicAdd(&hist2[tmp[i].w & 255], 1);
    __syncthreads();
    // exclusive scan of hist2
    int v = hist2[t];
    lds[t] = v;
    __syncthreads();
    for (int off = 1; off < 256; off <<= 1) {
        int x = (t >= off) ? lds[t - off] : 0;
        __syncthreads();
        lds[t] += x;
        __syncthreads();
    }
    int pre = lds[t] - v;
    cursor[t] = pre;
    int node = k * 256 + t;
    if (node <= N_NODES) row_start[node] = beg + pre;   // node==N_NODES lands here for k=195,t=80
    if (k == NBUCK - 1 && t == 255 && N_NODES > node) row_start[N_NODES] = end; // safety (unreached for these dims)
    __syncthreads();
    for (int i = beg + t; i < end; i += 256) {
        int4 ent = tmp[i];
        int slot = beg + atomicAdd(&cursor[ent.w & 255], 1);
        csr[slot] = ent;
    }
}

// ---------------- layer-1 projection: lane = node, scalar weights ----------------
__global__ __launch_bounds__(256) void proj1_kernel(
        const float* __restrict__ xin,        // C fp32 [N,64]
        const __half2* __restrict__ wt,       // [128][32] half2
        const float* __restrict__ bb,         // [128]
        __half2* __restrict__ xlh, __half2* __restrict__ xrh) {
    int g = __builtin_amdgcn_readfirstlane((int)(threadIdx.x >> 6));  // chan group 0..3
    int lane = threadIdx.x & 63;
    int node = blockIdx.x * 64 + lane;
    if (node >= N_NODES) return;

    h2v xrow[32];
    const float4* xp = (const float4*)(xin + node * 64);
#pragma unroll
    for (int q = 0; q < 16; ++q) {
        float4 v = xp[q];
        __half2 a = __floats2half2_rn(v.x, v.y);
        __half2 b = __floats2half2_rn(v.z, v.w);
        xrow[2 * q]     = *reinterpret_cast<h2v*>(&a);
        xrow[2 * q + 1] = *reinterpret_cast<h2v*>(&b);
    }

    __half2* outp = (g < 2) ? xlh : xrh;
    int chbase = g * 32;
    int localbase = (g & 1) * 16;

#pragma unroll
    for (int cp = 0; cp < 16; ++cp) {
        int ch0 = chbase + 2 * cp;
        const h2v* w0 = (const h2v*)(wt + ch0 * 32);
        const h2v* w1 = (const h2v*)(wt + (ch0 + 1) * 32);
        float a0 = bb[ch0], a1 = bb[ch0 + 1];
#pragma unroll
        for (int kk = 0; kk < 32; ++kk) {
            a0 = fdot2f(xrow[kk], w0[kk], a0);
            a1 = fdot2f(xrow[kk], w1[kk], a1);
        }
        outp[node * 32 + localbase + cp] = __floats2half2_rn(a0, a1);
    }
}

// ---------------- pass A: per-edge score, lane = edge ----------------
__global__ __launch_bounds__(256) void score_kernel(
        const int4* __restrict__ csr,
        const __half2* __restrict__ xlh, const __half2* __restrict__ xrh,
        const __half2* __restrict__ weh, const float* __restrict__ att,
        float* __restrict__ score) {
    int e = blockIdx.x * blockDim.x + threadIdx.x;
    if (e >= N_EDGES) return;
    int4 ent = csr[e];
    __half2 ea01 = *reinterpret_cast<__half2*>(&ent.y);
    __half2 ea23 = *reinterpret_cast<__half2*>(&ent.z);
    __half2 e0 = __half2half2(__low2half(ea01));
    __half2 e1 = __half2half2(__high2half(ea01));
    __half2 e2 = __half2half2(__low2half(ea23));
    __half2 e3 = __half2half2(__high2half(ea23));
    const int4* xa = (const int4*)(xlh + ent.x * 32);
    const int4* xb = (const int4*)(xrh + ent.w * 32);
    float acc0 = 0.f, acc1 = 0.f;
#pragma unroll
    for (int k = 0; k < 8; ++k) {
        int4 va = xa[k];
        int4 vb = xb[k];
        const __half2* ha = reinterpret_cast<const __half2*>(&va);
        const __half2* hc = reinterpret_cast<const __half2*>(&vb);
#pragma unroll
        for (int j = 0; j < 4; ++j) {
            int c = k * 4 + j;                     // uniform -> scalar loads
            __half2 v2 = __hadd2(ha[j], hc[j]);
            v2 = __hfma2(e0, weh[c * 4 + 0], v2);
            v2 = __hfma2(e1, weh[c * 4 + 1], v2);
            v2 = __hfma2(e2, weh[c * 4 + 2], v2);
            v2 = __hfma2(e3, weh[c * 4 + 3], v2);
            float2 vf = __half22float2(v2);
            float L0 = fmaxf(vf.x, SLOPE * vf.x);  // leaky_relu (slope<1)
            float L1 = fmaxf(vf.y, SLOPE * vf.y);
            float2 a2 = ((const float2*)att)[c];
            acc0 += L0 * a2.x;
            acc1 += L1 * a2.y;
        }
    }
    score[e] = acc0 + acc1;
}

// ---------------- pass B: aggregation, one wave per node ----------------
__global__ __launch_bounds__(256) void agg_kernel(
        const int* __restrict__ row_start,
        const int4* __restrict__ csr,
        const float* __restrict__ score,
        const __half2* __restrict__ xlh,
        const float* __restrict__ bias,
        float* __restrict__ out) {
    int wave = (blockIdx.x * blockDim.x + threadIdx.x) >> 6;
    if (wave >= N_NODES) return;
    int lane = threadIdx.x & 63;
    int c = lane & 31;
    int hb = lane >> 5;
    int d = wave;
    int beg = __builtin_amdgcn_readfirstlane(row_start[d]);
    int end = __builtin_amdgcn_readfirstlane(row_start[d + 1]);

    float m = -INFINITY;
    for (int j = beg + lane; j < end; j += 64) m = fmaxf(m, score[j]);
    m = lane63_bcast(wave_max_to63(m));

    float l_lane = 0.f;
    float ax0 = 0.f, ay0 = 0.f, ax1 = 0.f, ay1 = 0.f;

    for (int cbeg = beg; cbeg < end; cbeg += 64) {
        int n = end - cbeg;
        int idx = cbeg + lane;
        float sc = score[min(idx, end - 1)];
        float p = __expf(sc - m);
        p = (lane < n) ? p : 0.f;
        l_lane += p;

        int nn = min(n, 64);
        int j = 0;
        for (; j + 4 <= nn; j += 4) {
            int sA0 = __builtin_amdgcn_readfirstlane(csr[cbeg + j + 0].x);
            int sB0 = __builtin_amdgcn_readfirstlane(csr[cbeg + j + 1].x);
            int sA1 = __builtin_amdgcn_readfirstlane(csr[cbeg + j + 2].x);
            int sB1 = __builtin_amdgcn_readfirstlane(csr[cbeg + j + 3].x);
            float pA0 = readlane_f(p, j + 0), pB0 = readlane_f(p, j + 1);
            float pA1 = readlane_f(p, j + 2), pB1 = readlane_f(p, j + 3);
            int s0 = hb ? sB0 : sA0;
            int s1 = hb ? sB1 : sA1;
            float pv0 = hb ? pB0 : pA0;
            float pv1 = hb ? pB1 : pA1;
            float2 x0 = __half22float2(xlh[s0 * 32 + c]);
            float2 x1 = __half22float2(xlh[s1 * 32 + c]);
            ax0 += pv0 * x0.x; ay0 += pv0 * x0.y;
            ax1 += pv1 * x1.x; ay1 += pv1 * x1.y;
        }
        for (; j + 2 <= nn; j += 2) {
            int sA = __builtin_amdgcn_readfirstlane(csr[cbeg + j + 0].x);
            int sB = __builtin_amdgcn_readfirstlane(csr[cbeg + j + 1].x);
            float pA = readlane_f(p, j + 0), pB = readlane_f(p, j + 1);
            int s = hb ? sB : sA;
            float pv = hb ? pB : pA;
            float2 xf = __half22float2(xlh[s * 32 + c]);
            ax0 += pv * xf.x; ay0 += pv * xf.y;
        }
        if (j < nn) {
            int sA = __builtin_amdgcn_readfirstlane(csr[cbeg + j].x);
            float pA = readlane_f(p, j);
            float pv = hb ? 0.f : pA;
            float2 xf = __half22float2(xlh[sA * 32 + c]);
            ax0 += pv * xf.x; ay0 += pv * xf.y;
        }
    }

    float l = lane63_bcast(wave_sum_to63(l_lane));
    float accx = ax0 + ax1, accy = ay0 + ay1;
    accx += __shfl_xor(accx, 32, 64);
    accy += __shfl_xor(accy, 32, 64);
    if (hb == 0) {
        float inv = 1.f / (l + 1e-16f);
        float2 b2 = ((const float2*)bias)[c];
        float o0 = accx * inv + b2.x;
        float o1 = accy * inv + b2.y;
        o0 = o0 > 0.f ? o0 : expm1f(o0);
        o1 = o1 > 0.f ? o1 : expm1f(o1);
        ((float2*)out)[d * 32 + c] = float2{o0, o1};
    }
}

// ---------------- fused pool + head: one block per graph ----------------
__global__ __launch_bounds__(256) void pool_head_kernel(
        const float* __restrict__ h, const int* __restrict__ batch,
        const float* __restrict__ fc1w, const float* __restrict__ fc1b,
        const float* __restrict__ fc2w, const float* __restrict__ fc2b,
        float* __restrict__ out) {
    int g = blockIdx.x;
    int lo = 0, hi = N_NODES;
    while (lo < hi) { int mid = (lo + hi) >> 1; if (batch[mid] < g) lo = mid + 1; else hi = mid; }
    int start = lo;
    hi = N_NODES;
    while (lo < hi) { int mid = (lo + hi) >> 1; if (batch[mid] < g + 1) lo = mid + 1; else hi = mid; }
    int end = lo;

    int lane = threadIdx.x & 63;
    int w = threadIdx.x >> 6;
    float s = 0.f;
    for (int n = start + w; n < end; n += 4) s += h[n * H + lane];
    __shared__ float red[4][H];
    __shared__ float gv[H];
    __shared__ float f[FC];
    __shared__ float lg[NC];
    red[w][lane] = s;
    __syncthreads();
    if (w == 0) {
        float tot = red[0][lane] + red[1][lane] + red[2][lane] + red[3][lane];
        gv[lane] = tot / fmaxf((float)(end - start), 1.f);
    }
    __syncthreads();
    int t = threadIdx.x;
    if (t < FC) {
        float acc = fc1b[t];
#pragma unroll 16
        for (int k = 0; k < H; ++k) acc += gv[k] * fc1w[k * FC + t];
        f[t] = fmaxf(acc, 0.f);
    }
    __syncthreads();
    if (t < NC) {
        float a = fc2b[t];
        for (int k = 0; k < FC; ++k) a += f[k] * fc2w[k * NC + t];
        lg[t] = a;
    }
    __syncthreads();
    if (t < NC) {
        float mx = fmaxf(lg[0], lg[1]);
        float lse = mx + logf(expf(lg[0] - mx) + expf(lg[1] - mx));
        out[g * NC + t] = lg[t] - lse;
    }
}

extern "C" void kernel_launch(void* const* d_in, const int* in_sizes, int n_in,
                              void* d_out, int out_size, void* d_ws, size_t ws_size,
                              hipStream_t stream) {
    const float* x         = (const float*)d_in[0];
    const int*   edge_idx  = (const int*)d_in[1];
    const float* edge_attr = (const float*)d_in[2];
    const int*   batch     = (const int*)d_in[3];
    const float* Wl0  = (const float*)d_in[4];
    const float* bl0  = (const float*)d_in[5];
    const float* Wr0  = (const float*)d_in[6];
    const float* br0  = (const float*)d_in[7];
    const float* We0  = (const float*)d_in[8];
    const float* att0 = (const float*)d_in[9];
    const float* bias0= (const float*)d_in[10];
    const float* Wl1  = (const float*)d_in[11];
    const float* bl1  = (const float*)d_in[12];
    const float* Wr1  = (const float*)d_in[13];
    const float* br1  = (const float*)d_in[14];
    const float* We1  = (const float*)d_in[15];
    const float* att1 = (const float*)d_in[16];
    const float* bias1= (const float*)d_in[17];
    const float* fc1w = (const float*)d_in[18];
    const float* fc1b = (const float*)d_in[19];
    const float* fc2w = (const float*)d_in[20];
    const float* fc2b = (const float*)d_in[21];

    const int NH = N_NODES * H;
    __half2* xlh    = (__half2*)d_ws;                 // [N*32]  6.4MB
    __half2* xrh    = xlh + N_NODES * 32;             // [N*32]  6.4MB
    float* C        = (float*)(xrh + N_NODES * 32);   // [N,H] fp32 12.8MB ┐
    float* escore   = C + NH;                         // [E]          6.4 ├ tmp aliases these
    float* pad      = escore + N_EDGES;               // [E]          6.4 ┘
    int4*  tmp      = (int4*)C;                       // [E] 25.6MB (dead after fine_sort)
    int4*  csr      = (int4*)(pad + N_EDGES);         // [E] 25.6MB
    int*   row_start= (int*)(csr + N_EDGES);          // [N+1]
    int*   rank1    = row_start + N_NODES + 1;        // [E]
    int*   bhist    = rank1 + N_EDGES;                // [NB1*NBUCK]
    int*   bases    = bhist + NB1 * NBUCK;            // [NB1*NBUCK]
    int*   cb_start = bases + NB1 * NBUCK;            // [NBUCK+1]
    __half2* weh0   = (__half2*)(cb_start + NBUCK + 1);
    __half2* weh1   = weh0 + 128;
    __half2* wt1    = weh1 + 128;                     // [128*32]
    float* bb1      = (float*)(wt1 + 128 * 32);       // [128]

    const int* src = edge_idx;
    const int* dst = edge_idx + N_EDGES;

    const int edgeBlocks = (N_EDGES + 255) / 256;
    const int waveBlocks = (N_NODES * 64 + 255) / 256;
    const int p1Blocks   = (N_NODES + 63) / 64;
    const int frontBlocks = NB1 + PAIR_BLOCKS + 1;

    // ---- CSR build via 2-pass radix (LDS atomics only) + proj0 + prep ----
    front_kernel<<<frontBlocks, 256, 0, stream>>>(dst, rank1, bhist,
                                                  x, Wl0, bl0, Wr0, br0, xlh, xrh,
                                                  We0, We1, Wl1, bl1, Wr1, br1,
                                                  weh0, weh1, wt1, bb1);
    bucket_scan_kernel<<<1, 256, 0, stream>>>(bhist, bases, cb_start);
    coarse_scatter_kernel<<<edgeBlocks, 256, 0, stream>>>(src, dst, rank1, bases, cb_start,
                                                          edge_attr, tmp);
    fine_sort_kernel<<<NBUCK, 256, 0, stream>>>(cb_start, tmp, csr, row_start);

    // ---- layer 0 ----
    score_kernel<<<edgeBlocks, 256, 0, stream>>>(csr, xlh, xrh, weh0, att0, escore);
    agg_kernel<<<waveBlocks, 256, 0, stream>>>(row_start, csr, escore, xlh, bias0, C);

    // ---- layer 1 ----
    proj1_kernel<<<p1Blocks, 256, 0, stream>>>(C, wt1, bb1, xlh, xrh);
    score_kernel<<<edgeBlocks, 256, 0, stream>>>(csr, xlh, xrh, weh1, att1, escore);
    agg_kernel<<<waveBlocks, 256, 0, stream>>>(row_start, csr, escore, xlh, bias1, C);

    // ---- pool + head (fused) ----
    pool_head_kernel<<<G_GRAPHS, 256, 0, stream>>>(C, batch, fc1w, fc1b, fc2w, fc2b, (float*)d_out);
}

// Round 17
// 434.994 us; speedup vs baseline: 1.1803x; 1.0226x over previous
//
#include <hip/hip_runtime.h>
#include <hip/hip_fp16.h>

#define N_NODES 50000
#define N_EDGES 1600000
#define H 64
#define IN_CH 7
#define EDIM 4
#define G_GRAPHS 256
#define FC 128
#define NC 2
#define SLOPE 0.2f
#define NBUCK 196                      // coarse buckets: dst>>8
#define EPB1 8192                      // edges per pass-1a block
#define NB1 ((N_EDGES + EPB1 - 1) / EPB1)          // 196
#define PAIR_BLOCKS ((N_NODES * 32 + 255) / 256)   // 6250

typedef _Float16 h2v __attribute__((ext_vector_type(2)));

__device__ __forceinline__ float fdot2f(h2v a, h2v b, float c) {
#if defined(__has_builtin) && __has_builtin(__builtin_amdgcn_fdot2)
    return __builtin_amdgcn_fdot2(a, b, c, false);
#else
    return c + (float)a[0] * (float)b[0] + (float)a[1] * (float)b[1];
#endif
}

// order-preserving float<->uint encoding (for atomicMax on floats; 0 == "-inf")
__device__ __forceinline__ unsigned enc_f(float f) {
    unsigned b = __float_as_uint(f);
    return (b & 0x80000000u) ? ~b : (b | 0x80000000u);
}
__device__ __forceinline__ float dec_f(unsigned u) {
    return __uint_as_float((u & 0x80000000u) ? (u ^ 0x80000000u) : ~u);
}

// ---------------- DPP wave-64 reductions ----------------
__device__ __forceinline__ float wave_sum_to63(float x) {
    x += __int_as_float(__builtin_amdgcn_update_dpp(0, __float_as_int(x), 0x111, 0xf, 0xf, true)); // row_shr:1
    x += __int_as_float(__builtin_amdgcn_update_dpp(0, __float_as_int(x), 0x112, 0xf, 0xf, true)); // row_shr:2
    x += __int_as_float(__builtin_amdgcn_update_dpp(0, __float_as_int(x), 0x114, 0xf, 0xf, true)); // row_shr:4
    x += __int_as_float(__builtin_amdgcn_update_dpp(0, __float_as_int(x), 0x118, 0xf, 0xf, true)); // row_shr:8
    x += __int_as_float(__builtin_amdgcn_update_dpp(0, __float_as_int(x), 0x142, 0xf, 0xf, true)); // row_bcast:15
    x += __int_as_float(__builtin_amdgcn_update_dpp(0, __float_as_int(x), 0x143, 0xf, 0xf, true)); // row_bcast:31
    return x;
}
__device__ __forceinline__ float lane63_bcast(float x) {
    return __int_as_float(__builtin_amdgcn_readlane(__float_as_int(x), 63));
}
__device__ __forceinline__ float readlane_f(float x, int i) {
    return __int_as_float(__builtin_amdgcn_readlane(__float_as_int(x), i));
}

// ---------------- fused front-end: coarse histogram+rank (LDS atomics) + proj0 + prep ----------------
__global__ __launch_bounds__(256) void front_kernel(
        const int* __restrict__ dst, int* __restrict__ rank1, int* __restrict__ bhist,
        const float* __restrict__ xin,
        const float* __restrict__ Wl0, const float* __restrict__ bl0,
        const float* __restrict__ Wr0, const float* __restrict__ br0,
        __half2* __restrict__ xlh, __half2* __restrict__ xrh,
        const float* __restrict__ We0, const float* __restrict__ We1,
        const float* __restrict__ Wl1, const float* __restrict__ bl1,
        const float* __restrict__ Wr1, const float* __restrict__ br1,
        __half2* __restrict__ weh0, __half2* __restrict__ weh1,
        __half2* __restrict__ wt, float* __restrict__ bb) {
    __shared__ int hist[NBUCK];
    int b = blockIdx.x;
    int t = threadIdx.x;
    if (b < NB1) {
        if (t < NBUCK) hist[t] = 0;
        __syncthreads();
#pragma unroll
        for (int i = 0; i < EPB1 / 256; ++i) {
            int e = b * EPB1 + i * 256 + t;
            if (e < N_EDGES) {
                int k = dst[e] >> 8;
                rank1[e] = atomicAdd(&hist[k], 1);
            }
        }
        __syncthreads();
        if (t < NBUCK) bhist[b * NBUCK + t] = hist[t];
    } else if (b < NB1 + PAIR_BLOCKS) {
        int idx = (b - NB1) * 256 + t;
        if (idx < N_NODES * 32) {
            int n = idx >> 5;
            int c = idx & 31;
            const float* xi = xin + n * IN_CH;
            float2 bl2 = ((const float2*)bl0)[c];
            float2 br2 = ((const float2*)br0)[c];
            float al0 = bl2.x, al1 = bl2.y, ar0 = br2.x, ar1 = br2.y;
#pragma unroll
            for (int k = 0; k < IN_CH; ++k) {
                float xv = xi[k];
                float2 wl2 = ((const float2*)(Wl0 + k * H))[c];
                float2 wr2 = ((const float2*)(Wr0 + k * H))[c];
                al0 += xv * wl2.x; al1 += xv * wl2.y;
                ar0 += xv * wr2.x; ar1 += xv * wr2.y;
            }
            xlh[idx] = __floats2half2_rn(al0, al1);
            xrh[idx] = __floats2half2_rn(ar0, ar1);
        }
    } else {
        if (t < 32) {
            for (int k = 0; k < 4; ++k)
                weh0[t * 4 + k] = __floats2half2_rn(We0[k * H + 2 * t], We0[k * H + 2 * t + 1]);
        } else if (t < 64) {
            int c = t - 32;
            for (int k = 0; k < 4; ++k)
                weh1[c * 4 + k] = __floats2half2_rn(We1[k * H + 2 * c], We1[k * H + 2 * c + 1]);
        }
        if (t < 128) {
            const float* W = (t < 64) ? Wl1 : Wr1;
            int c = t & 63;
            for (int kk = 0; kk < 32; ++kk)
                wt[t * 32 + kk] = __floats2half2_rn(W[(2 * kk) * H + c], W[(2 * kk + 1) * H + c]);
            bb[t] = (t < 64) ? bl1[c] : br1[c];
        }
    }
}

// single block: per-(block,bucket) bases + bucket starts
__global__ __launch_bounds__(256) void bucket_scan_kernel(
        const int* __restrict__ bhist, int* __restrict__ bases, int* __restrict__ cb_start) {
    __shared__ int lds[256];
    int t = threadIdx.x;
    int run = 0;
    if (t < NBUCK) {
        for (int b = 0; b < NB1; ++b) {
            bases[b * NBUCK + t] = run;
            run += bhist[b * NBUCK + t];
        }
    }
    lds[t] = (t < NBUCK) ? run : 0;
    __syncthreads();
    for (int off = 1; off < 256; off <<= 1) {
        int x = (t >= off) ? lds[t - off] : 0;
        __syncthreads();
        lds[t] += x;
        __syncthreads();
    }
    if (t < NBUCK) cb_start[t] = lds[t] - run;
    if (t == NBUCK - 1) cb_start[NBUCK] = lds[t];
}

// coarse scatter: edge -> bucket-sorted tmp
__global__ void coarse_scatter_kernel(const int* __restrict__ src, const int* __restrict__ dst,
                                      const int* __restrict__ rank1, const int* __restrict__ bases,
                                      const int* __restrict__ cb_start,
                                      const float* __restrict__ edge_attr,
                                      int4* __restrict__ tmp) {
    int e = blockIdx.x * blockDim.x + threadIdx.x;
    if (e >= N_EDGES) return;
    int d = dst[e];
    int k = d >> 8;
    int b = e / EPB1;
    int slot = cb_start[k] + bases[b * NBUCK + k] + rank1[e];
    float4 ea = ((const float4*)edge_attr)[e];
    __half2 h01 = __floats2half2_rn(ea.x, ea.y);
    __half2 h23 = __floats2half2_rn(ea.z, ea.w);
    int4 ent;
    ent.x = src[e];
    ent.y = *reinterpret_cast<int*>(&h01);
    ent.z = *reinterpret_cast<int*>(&h23);
    ent.w = d;
    tmp[slot] = ent;
}

// fine sort: one block per coarse bucket; emits csr + srcs + row_start + zeroed m_enc.
__global__ __launch_bounds__(256) void fine_sort_kernel(
        const int* __restrict__ cb_start, const int4* __restrict__ tmp,
        int4* __restrict__ csr, int* __restrict__ srcs,
        int* __restrict__ row_start, unsigned* __restrict__ m_enc) {
    __shared__ int hist2[256];
    __shared__ int cursor[256];
    __shared__ int lds[256];
    int k = blockIdx.x;
    int t = threadIdx.x;
    int beg = cb_start[k], end = cb_start[k + 1];
    hist2[t] = 0;
    __syncthreads();
    for (int i = beg + t; i < end; i += 256)
        atomicAdd(&hist2[tmp[i].w & 255], 1);
    __syncthreads();
    int v = hist2[t];
    lds[t] = v;
    __syncthreads();
    for (int off = 1; off < 256; off <<= 1) {
        int x = (t >= off) ? lds[t - off] : 0;
        __syncthreads();
        lds[t] += x;
        __syncthreads();
    }
    int pre = lds[t] - v;
    cursor[t] = pre;
    int node = k * 256 + t;
    if (node <= N_NODES) row_start[node] = beg + pre;
    if (node < N_NODES) m_enc[node] = 0u;      // "-inf" in order-preserving encoding
    __syncthreads();
    for (int i = beg + t; i < end; i += 256) {
        int4 ent = tmp[i];
        int slot = beg + atomicAdd(&cursor[ent.w & 255], 1);
        csr[slot] = ent;
        srcs[slot] = ent.x;
    }
}

// ---------------- layer-1 projection: lane = node, scalar weights ----------------
__global__ __launch_bounds__(256) void proj1_kernel(
        const float* __restrict__ xin,
        const __half2* __restrict__ wt,
        const float* __restrict__ bb,
        __half2* __restrict__ xlh, __half2* __restrict__ xrh) {
    int g = __builtin_amdgcn_readfirstlane((int)(threadIdx.x >> 6));
    int lane = threadIdx.x & 63;
    int node = blockIdx.x * 64 + lane;
    if (node >= N_NODES) return;

    h2v xrow[32];
    const float4* xp = (const float4*)(xin + node * 64);
#pragma unroll
    for (int q = 0; q < 16; ++q) {
        float4 v = xp[q];
        __half2 a = __floats2half2_rn(v.x, v.y);
        __half2 b = __floats2half2_rn(v.z, v.w);
        xrow[2 * q]     = *reinterpret_cast<h2v*>(&a);
        xrow[2 * q + 1] = *reinterpret_cast<h2v*>(&b);
    }

    __half2* outp = (g < 2) ? xlh : xrh;
    int chbase = g * 32;
    int localbase = (g & 1) * 16;

#pragma unroll
    for (int cp = 0; cp < 16; ++cp) {
        int ch0 = chbase + 2 * cp;
        const h2v* w0 = (const h2v*)(wt + ch0 * 32);
        const h2v* w1 = (const h2v*)(wt + (ch0 + 1) * 32);
        float a0 = bb[ch0], a1 = bb[ch0 + 1];
#pragma unroll
        for (int kk = 0; kk < 32; ++kk) {
            a0 = fdot2f(xrow[kk], w0[kk], a0);
            a1 = fdot2f(xrow[kk], w1[kk], a1);
        }
        outp[node * 32 + localbase + cp] = __floats2half2_rn(a0, a1);
    }
}

// ---------------- pass A: per-edge score (lane = edge) + segmented per-node max ----------------
// N_EDGES % 256 == 0 -> no tail; no divergent returns (block-wide __syncthreads below).
__global__ __launch_bounds__(256) void score_kernel(
        const int4* __restrict__ csr,
        const __half2* __restrict__ xlh, const __half2* __restrict__ xrh,
        const __half2* __restrict__ weh, const float* __restrict__ att,
        float* __restrict__ score, unsigned* __restrict__ m_enc) {
    __shared__ int sdst[256];
    __shared__ float ssc[256];
    int t = threadIdx.x;
    int e = blockIdx.x * 256 + t;
    int4 ent = csr[e];
    __half2 ea01 = *reinterpret_cast<__half2*>(&ent.y);
    __half2 ea23 = *reinterpret_cast<__half2*>(&ent.z);
    __half2 e0 = __half2half2(__low2half(ea01));
    __half2 e1 = __half2half2(__high2half(ea01));
    __half2 e2 = __half2half2(__low2half(ea23));
    __half2 e3 = __half2half2(__high2half(ea23));
    const int4* xa = (const int4*)(xlh + ent.x * 32);
    const int4* xb = (const int4*)(xrh + ent.w * 32);
    float acc0 = 0.f, acc1 = 0.f;
#pragma unroll
    for (int k = 0; k < 8; ++k) {
        int4 va = xa[k];
        int4 vb = xb[k];
        const __half2* ha = reinterpret_cast<const __half2*>(&va);
        const __half2* hc = reinterpret_cast<const __half2*>(&vb);
#pragma unroll
        for (int j = 0; j < 4; ++j) {
            int c = k * 4 + j;                     // uniform -> scalar loads
            __half2 v2 = __hadd2(ha[j], hc[j]);
            v2 = __hfma2(e0, weh[c * 4 + 0], v2);
            v2 = __hfma2(e1, weh[c * 4 + 1], v2);
            v2 = __hfma2(e2, weh[c * 4 + 2], v2);
            v2 = __hfma2(e3, weh[c * 4 + 3], v2);
            float2 vf = __half22float2(v2);
            float L0 = fmaxf(vf.x, SLOPE * vf.x);
            float L1 = fmaxf(vf.y, SLOPE * vf.y);
            float2 a2 = ((const float2*)att)[c];
            acc0 += L0 * a2.x;
            acc1 += L1 * a2.y;
        }
    }
    float sc = acc0 + acc1;
    score[e] = sc;
    // segmented per-node max (edges are dst-sorted): ~9 atomics per block
    sdst[t] = ent.w;
    ssc[t] = sc;
    __syncthreads();
    bool head = (t == 0) || (sdst[t] != sdst[t - 1]);
    if (head) {
        float mx = ssc[t];
        for (int i = t + 1; i < 256 && sdst[i] == sdst[t]; ++i) mx = fmaxf(mx, ssc[i]);
        atomicMax(&m_enc[sdst[t]], enc_f(mx));
    }
}

// ---------------- pass B: aggregation, one wave per node (max precomputed) ----------------
__global__ __launch_bounds__(256) void agg_kernel(
        const int* __restrict__ row_start,
        const int* __restrict__ srcs,
        const float* __restrict__ score,
        unsigned* __restrict__ m_enc,
        const __half2* __restrict__ xlh,
        const float* __restrict__ bias,
        float* __restrict__ out) {
    int wave = (blockIdx.x * blockDim.x + threadIdx.x) >> 6;
    if (wave >= N_NODES) return;
    int lane = threadIdx.x & 63;
    int c = lane & 31;
    int hb = lane >> 5;
    int d = wave;
    int beg = __builtin_amdgcn_readfirstlane(row_start[d]);
    int end = __builtin_amdgcn_readfirstlane(row_start[d + 1]);
    float m = dec_f(__builtin_amdgcn_readfirstlane(m_enc[d]));

    float l_lane = 0.f;
    float ax0 = 0.f, ay0 = 0.f, ax1 = 0.f, ay1 = 0.f;

    for (int cbeg = beg; cbeg < end; cbeg += 64) {
        int n = end - cbeg;
        float sc = score[cbeg + lane];        // reads past end land in pad; masked below
        float p = __expf(sc - m);
        p = (lane < n) ? p : 0.f;
        l_lane += p;

        int nn = min(n, 64);
        int j = 0;
        for (; j + 4 <= nn; j += 4) {
            int sA0 = __builtin_amdgcn_readfirstlane(srcs[cbeg + j + 0]);
            int sB0 = __builtin_amdgcn_readfirstlane(srcs[cbeg + j + 1]);
            int sA1 = __builtin_amdgcn_readfirstlane(srcs[cbeg + j + 2]);
            int sB1 = __builtin_amdgcn_readfirstlane(srcs[cbeg + j + 3]);
            float pA0 = readlane_f(p, j + 0), pB0 = readlane_f(p, j + 1);
            float pA1 = readlane_f(p, j + 2), pB1 = readlane_f(p, j + 3);
            int s0 = hb ? sB0 : sA0;
            int s1 = hb ? sB1 : sA1;
            float pv0 = hb ? pB0 : pA0;
            float pv1 = hb ? pB1 : pA1;
            float2 x0 = __half22float2(xlh[s0 * 32 + c]);
            float2 x1 = __half22float2(xlh[s1 * 32 + c]);
            ax0 += pv0 * x0.x; ay0 += pv0 * x0.y;
            ax1 += pv1 * x1.x; ay1 += pv1 * x1.y;
        }
        for (; j + 2 <= nn; j += 2) {
            int sA = __builtin_amdgcn_readfirstlane(srcs[cbeg + j + 0]);
            int sB = __builtin_amdgcn_readfirstlane(srcs[cbeg + j + 1]);
            float pA = readlane_f(p, j + 0), pB = readlane_f(p, j + 1);
            int s = hb ? sB : sA;
            float pv = hb ? pB : pA;
            float2 xf = __half22float2(xlh[s * 32 + c]);
            ax0 += pv * xf.x; ay0 += pv * xf.y;
        }
        if (j < nn) {
            int sA = __builtin_amdgcn_readfirstlane(srcs[cbeg + j]);
            float pA = readlane_f(p, j);
            float pv = hb ? 0.f : pA;
            float2 xf = __half22float2(xlh[sA * 32 + c]);
            ax0 += pv * xf.x; ay0 += pv * xf.y;
        }
    }

    float l = lane63_bcast(wave_sum_to63(l_lane));
    float accx = ax0 + ax1, accy = ay0 + ay1;
    accx += __shfl_xor(accx, 32, 64);
    accy += __shfl_xor(accy, 32, 64);
    if (hb == 0) {
        float inv = 1.f / (l + 1e-16f);
        float2 b2 = ((const float2*)bias)[c];
        float o0 = accx * inv + b2.x;
        float o1 = accy * inv + b2.y;
        o0 = o0 > 0.f ? o0 : expm1f(o0);
        o1 = o1 > 0.f ? o1 : expm1f(o1);
        ((float2*)out)[d * 32 + c] = float2{o0, o1};
        if (lane == 0) m_enc[d] = 0u;   // re-arm for next layer's score pass
    }
}

// ---------------- fused pool + head: one block per graph ----------------
__global__ __launch_bounds__(256) void pool_head_kernel(
        const float* __restrict__ h, const int* __restrict__ batch,
        const float* __restrict__ fc1w, const float* __restrict__ fc1b,
        const float* __restrict__ fc2w, const float* __restrict__ fc2b,
        float* __restrict__ out) {
    int g = blockIdx.x;
    int lo = 0, hi = N_NODES;
    while (lo < hi) { int mid = (lo + hi) >> 1; if (batch[mid] < g) lo = mid + 1; else hi = mid; }
    int start = lo;
    hi = N_NODES;
    while (lo < hi) { int mid = (lo + hi) >> 1; if (batch[mid] < g + 1) lo = mid + 1; else hi = mid; }
    int end = lo;

    int lane = threadIdx.x & 63;
    int w = threadIdx.x >> 6;
    float s = 0.f;
    for (int n = start + w; n < end; n += 4) s += h[n * H + lane];
    __shared__ float red[4][H];
    __shared__ float gv[H];
    __shared__ float f[FC];
    __shared__ float lg[NC];
    red[w][lane] = s;
    __syncthreads();
    if (w == 0) {
        float tot = red[0][lane] + red[1][lane] + red[2][lane] + red[3][lane];
        gv[lane] = tot / fmaxf((float)(end - start), 1.f);
    }
    __syncthreads();
    int t = threadIdx.x;
    if (t < FC) {
        float acc = fc1b[t];
#pragma unroll 16
        for (int k = 0; k < H; ++k) acc += gv[k] * fc1w[k * FC + t];
        f[t] = fmaxf(acc, 0.f);
    }
    __syncthreads();
    if (t < NC) {
        float a = fc2b[t];
        for (int k = 0; k < FC; ++k) a += f[k] * fc2w[k * NC + t];
        lg[t] = a;
    }
    __syncthreads();
    if (t < NC) {
        float mx = fmaxf(lg[0], lg[1]);
        float lse = mx + logf(expf(lg[0] - mx) + expf(lg[1] - mx));
        out[g * NC + t] = lg[t] - lse;
    }
}

extern "C" void kernel_launch(void* const* d_in, const int* in_sizes, int n_in,
                              void* d_out, int out_size, void* d_ws, size_t ws_size,
                              hipStream_t stream) {
    const float* x         = (const float*)d_in[0];
    const int*   edge_idx  = (const int*)d_in[1];
    const float* edge_attr = (const float*)d_in[2];
    const int*   batch     = (const int*)d_in[3];
    const float* Wl0  = (const float*)d_in[4];
    const float* bl0  = (const float*)d_in[5];
    const float* Wr0  = (const float*)d_in[6];
    const float* br0  = (const float*)d_in[7];
    const float* We0  = (const float*)d_in[8];
    const float* att0 = (const float*)d_in[9];
    const float* bias0= (const float*)d_in[10];
    const float* Wl1  = (const float*)d_in[11];
    const float* bl1  = (const float*)d_in[12];
    const float* Wr1  = (const float*)d_in[13];
    const float* br1  = (const float*)d_in[14];
    const float* We1  = (const float*)d_in[15];
    const float* att1 = (const float*)d_in[16];
    const float* bias1= (const float*)d_in[17];
    const float* fc1w = (const float*)d_in[18];
    const float* fc1b = (const float*)d_in[19];
    const float* fc2w = (const float*)d_in[20];
    const float* fc2b = (const float*)d_in[21];

    const int NH = N_NODES * H;
    __half2* xlh    = (__half2*)d_ws;                 // [N*32]
    __half2* xrh    = xlh + N_NODES * 32;             // [N*32]
    float* C        = (float*)(xrh + N_NODES * 32);   // [N,H] fp32 ┐
    float* escore   = C + NH;                         // [E]        ├ tmp aliases these
    float* pad      = escore + N_EDGES;               // [E]        ┘
    int4*  tmp      = (int4*)C;                       // [E] (dead after fine_sort)
    int4*  csr      = (int4*)(pad + N_EDGES);         // [E]
    int*   srcs     = (int*)(csr + N_EDGES);          // [E]
    int*   row_start= srcs + N_EDGES;                 // [N+1]
    unsigned* m_enc = (unsigned*)(row_start + N_NODES + 1); // [N]
    int*   rank1    = (int*)(m_enc + N_NODES);        // [E]
    int*   bhist    = rank1 + N_EDGES;                // [NB1*NBUCK]
    int*   bases    = bhist + NB1 * NBUCK;            // [NB1*NBUCK]
    int*   cb_start = bases + NB1 * NBUCK;            // [NBUCK+1]
    __half2* weh0   = (__half2*)(cb_start + NBUCK + 1);
    __half2* weh1   = weh0 + 128;
    __half2* wt1    = weh1 + 128;                     // [128*32]
    float* bb1      = (float*)(wt1 + 128 * 32);       // [128]

    const int* src = edge_idx;
    const int* dst = edge_idx + N_EDGES;

    const int edgeBlocks = (N_EDGES + 255) / 256;
    const int waveBlocks = (N_NODES * 64 + 255) / 256;
    const int p1Blocks   = (N_NODES + 63) / 64;
    const int frontBlocks = NB1 + PAIR_BLOCKS + 1;

    // ---- CSR build via 2-pass radix (LDS atomics only) + proj0 + prep ----
    front_kernel<<<frontBlocks, 256, 0, stream>>>(dst, rank1, bhist,
                                                  x, Wl0, bl0, Wr0, br0, xlh, xrh,
                                                  We0, We1, Wl1, bl1, Wr1, br1,
                                                  weh0, weh1, wt1, bb1);
    bucket_scan_kernel<<<1, 256, 0, stream>>>(bhist, bases, cb_start);
    coarse_scatter_kernel<<<edgeBlocks, 256, 0, stream>>>(src, dst, rank1, bases, cb_start,
                                                          edge_attr, tmp);
    fine_sort_kernel<<<NBUCK, 256, 0, stream>>>(cb_start, tmp, csr, srcs, row_start, m_enc);

    // ---- layer 0 ----
    score_kernel<<<edgeBlocks, 256, 0, stream>>>(csr, xlh, xrh, weh0, att0, escore, m_enc);
    agg_kernel<<<waveBlocks, 256, 0, stream>>>(row_start, srcs, escore, m_enc, xlh, bias0, C);

    // ---- layer 1 ----
    proj1_kernel<<<p1Blocks, 256, 0, stream>>>(C, wt1, bb1, xlh, xrh);
    score_kernel<<<edgeBlocks, 256, 0, stream>>>(csr, xlh, xrh, weh1, att1, escore, m_enc);
    agg_kernel<<<waveBlocks, 256, 0, stream>>>(row_start, srcs, escore, m_enc, xlh, bias1, C);

    // ---- pool + head (fused) ----
    pool_head_kernel<<<G_GRAPHS, 256, 0, stream>>>(C, batch, fc1w, fc1b, fc2w, fc2b, (float*)d_out);
}